// Round 1
// baseline (924.432 us; speedup 1.0000x reference)
//
#include <hip/hip_runtime.h>

// FeatureDecoder: 4x (Linear -> BN(batch stats) -> ReLU -> Linear) with gathers.
// Strategy: bf16 MFMA GEMMs (m97-style 128x128 tile, BK=64, global_load_lds w=16),
// BN split into GEMM1(+stats atomics) / finalize / GEMM2(affine+relu fused in A-staging).
// GEMM1 bias dropped (BN shift-invariant).

typedef unsigned short u16;
typedef __attribute__((ext_vector_type(8))) short bf16x8;
typedef __attribute__((ext_vector_type(4))) float f32x4;

__device__ __forceinline__ float b2f(u16 u) {
    union { unsigned int i; float f; } v; v.i = ((unsigned int)u) << 16; return v.f;
}
__device__ __forceinline__ u16 f2b(float f) {
    union { float f; unsigned int i; } v; v.f = f;
    unsigned int r = v.i + 0x7FFFu + ((v.i >> 16) & 1u);
    return (u16)(r >> 16);
}

__device__ __forceinline__ void gld_lds16(const u16* g, u16* l) {
    __builtin_amdgcn_global_load_lds(
        (const __attribute__((address_space(1))) unsigned int*)g,
        (__attribute__((address_space(3))) unsigned int*)l,
        16, 0, 0);
}

// ---------------- GEMM: C(MxN) = A(MxK bf16) @ BT(NxK bf16)^T ----------------
// AFFINE_A: A is H; apply relu(H*scale+shift) per K-channel during staging.
// STATS: accumulate per-column sum/sumsq (of the pre-bias fp32 accumulator) via atomics.
// OUT_F32: write fp32, else bf16. bias (len N) added when !STATS.
template <bool AFFINE_A, bool STATS, bool OUT_F32>
__global__ __launch_bounds__(256) void gemm_bn(
    const u16* __restrict__ A, const u16* __restrict__ BT, void* __restrict__ Cout,
    const float* __restrict__ scale, const float* __restrict__ shift,
    const float* __restrict__ bias,
    float* __restrict__ psum, float* __restrict__ psumsq,
    int M, int N, int K)
{
    (void)M;
    __shared__ __align__(16) u16 sA[128 * 64];
    __shared__ __align__(16) u16 sB[128 * 64];

    const int tid  = threadIdx.x;
    const int w    = tid >> 6;
    const int lane = tid & 63;
    const int wm   = w & 1, wn = w >> 1;
    const int bm   = blockIdx.y, bn = blockIdx.x;

    // staging coords: each wave stages 32 rows (4 calls x 8 rows), lane L -> row L/8, col (L%8)*8
    const int srow = w * 32 + (lane >> 3);
    const int scol = (lane & 7) * 8;

    const u16* Ag = A  + (size_t)(bm * 128 + srow) * K + scol;
    const u16* Bg = BT + (size_t)(bn * 128 + srow) * K + scol;

    f32x4 acc[4][4];
    const f32x4 zero = {0.f, 0.f, 0.f, 0.f};
#pragma unroll
    for (int i = 0; i < 4; i++)
#pragma unroll
        for (int j = 0; j < 4; j++) acc[i][j] = zero;

    const int nkt = K >> 6;
    for (int kt = 0; kt < nkt; kt++) {
        const int kof = kt * 64;
        // ---- stage B (async global->LDS, 16B/lane) ----
#pragma unroll
        for (int q = 0; q < 4; q++)
            gld_lds16(Bg + (size_t)(q * 8) * K + kof, &sB[(w * 32 + q * 8) * 64]);
        // ---- stage A ----
        if constexpr (!AFFINE_A) {
#pragma unroll
            for (int q = 0; q < 4; q++)
                gld_lds16(Ag + (size_t)(q * 8) * K + kof, &sA[(w * 32 + q * 8) * 64]);
        } else {
            const float4 sc0 = *(const float4*)(scale + kof + scol);
            const float4 sc1 = *(const float4*)(scale + kof + scol + 4);
            const float4 sh0 = *(const float4*)(shift + kof + scol);
            const float4 sh1 = *(const float4*)(shift + kof + scol + 4);
#pragma unroll
            for (int q = 0; q < 4; q++) {
                union { uint4 u; u16 s[8]; } r, o;
                r.u = *(const uint4*)(Ag + (size_t)(q * 8) * K + kof);
                o.s[0] = f2b(fmaxf(b2f(r.s[0]) * sc0.x + sh0.x, 0.f));
                o.s[1] = f2b(fmaxf(b2f(r.s[1]) * sc0.y + sh0.y, 0.f));
                o.s[2] = f2b(fmaxf(b2f(r.s[2]) * sc0.z + sh0.z, 0.f));
                o.s[3] = f2b(fmaxf(b2f(r.s[3]) * sc0.w + sh0.w, 0.f));
                o.s[4] = f2b(fmaxf(b2f(r.s[4]) * sc1.x + sh1.x, 0.f));
                o.s[5] = f2b(fmaxf(b2f(r.s[5]) * sc1.y + sh1.y, 0.f));
                o.s[6] = f2b(fmaxf(b2f(r.s[6]) * sc1.z + sh1.z, 0.f));
                o.s[7] = f2b(fmaxf(b2f(r.s[7]) * sc1.w + sh1.w, 0.f));
                *(uint4*)&sA[(w * 32 + q * 8 + (lane >> 3)) * 64 + scol] = o.u;
            }
        }
        __syncthreads();
        // ---- compute: 2 k-steps of 32, 16 MFMA each ----
#pragma unroll
        for (int ks = 0; ks < 2; ks++) {
            const int kk = ks * 32 + (lane >> 4) * 8;
            bf16x8 af[4], bfr[4];
#pragma unroll
            for (int i = 0; i < 4; i++)
                af[i] = *(const bf16x8*)&sA[(wm * 64 + i * 16 + (lane & 15)) * 64 + kk];
#pragma unroll
            for (int j = 0; j < 4; j++)
                bfr[j] = *(const bf16x8*)&sB[(wn * 64 + j * 16 + (lane & 15)) * 64 + kk];
#pragma unroll
            for (int i = 0; i < 4; i++)
#pragma unroll
                for (int j = 0; j < 4; j++)
                    acc[i][j] = __builtin_amdgcn_mfma_f32_16x16x32_bf16(af[i], bfr[j], acc[i][j], 0, 0, 0);
        }
        __syncthreads();
    }

    // ---- epilogue: C/D layout col=lane&15, row=(lane>>4)*4+reg ----
    const int cl = lane & 15, quad = lane >> 4;
#pragma unroll
    for (int j = 0; j < 4; j++) {
        const int col = bn * 128 + wn * 64 + j * 16 + cl;
        float bcol = 0.f;
        if constexpr (!STATS) bcol = bias[col];
        float s = 0.f, ss = 0.f;
#pragma unroll
        for (int i = 0; i < 4; i++) {
            const size_t row0 = (size_t)(bm * 128 + wm * 64 + i * 16 + quad * 4);
#pragma unroll
            for (int r = 0; r < 4; r++) {
                const float v = acc[i][j][r];
                if constexpr (STATS) { s += v; ss += v * v; }
                const float o = v + bcol;
                if constexpr (OUT_F32)
                    ((float*)Cout)[(row0 + r) * N + col] = o;
                else
                    ((u16*)Cout)[(row0 + r) * N + col] = f2b(o);
            }
        }
        if constexpr (STATS) {
            s  += __shfl_xor(s, 16);  s  += __shfl_xor(s, 32);
            ss += __shfl_xor(ss, 16); ss += __shfl_xor(ss, 32);
            if (quad == 0) { atomicAdd(&psum[col], s); atomicAdd(&psumsq[col], ss); }
        }
    }
}

// ---------------- W (KxN fp32) -> WT (NxK bf16), tiled transpose ----------------
__global__ void cvt_transpose_w(const float* __restrict__ W, u16* __restrict__ WT, int K, int N) {
    __shared__ float t[32][33];
    const int tx = threadIdx.x, ty = threadIdx.y;
    const int n0 = blockIdx.x * 32, k0 = blockIdx.y * 32;
#pragma unroll
    for (int r = 0; r < 4; r++)
        t[ty + r * 8][tx] = W[(size_t)(k0 + ty + r * 8) * N + n0 + tx];
    __syncthreads();
#pragma unroll
    for (int r = 0; r < 4; r++)
        WT[(size_t)(n0 + ty + r * 8) * K + k0 + tx] = f2b(t[tx][ty + r * 8]);
}

// ---------------- fp32 -> bf16 elementwise (8 elems/thread) ----------------
__global__ void cvt_f32_bf16(const float* __restrict__ x, u16* __restrict__ y, long n8) {
    const long t = (long)blockIdx.x * 256 + threadIdx.x;
    if (t >= n8) return;
    const float4 a = ((const float4*)x)[t * 2];
    const float4 b = ((const float4*)x)[t * 2 + 1];
    union { uint4 u; u16 s[8]; } o;
    o.s[0] = f2b(a.x); o.s[1] = f2b(a.y); o.s[2] = f2b(a.z); o.s[3] = f2b(a.w);
    o.s[4] = f2b(b.x); o.s[5] = f2b(b.y); o.s[6] = f2b(b.z); o.s[7] = f2b(b.w);
    ((uint4*)y)[t] = o.u;
}

// ---------------- out[b,n,:] = [cvt(f[b,n,:]), X[b*Nc+pool[b,n],:]] (bf16) ----------------
__global__ void gather_concat(const float* __restrict__ f, const u16* __restrict__ X,
                              const int* __restrict__ pool, u16* __restrict__ out,
                              int Nf, int Nc, int Cc, int B) {
    const int per_row = (2 * Cc) / 8;
    const long t = (long)blockIdx.x * 256 + threadIdx.x;
    const long total = (long)B * Nf * per_row;
    if (t >= total) return;
    const int row = (int)(t / per_row);
    const int c8 = (int)(t % per_row) * 8;
    const int b = row / Nf, n = row % Nf;
    union { uint4 u; u16 s[8]; } o;
    if (c8 < Cc) {
        const float* src = f + (size_t)row * Cc + c8;
        const float4 a = *(const float4*)src;
        const float4 bb = *(const float4*)(src + 4);
        o.s[0] = f2b(a.x);  o.s[1] = f2b(a.y);  o.s[2] = f2b(a.z);  o.s[3] = f2b(a.w);
        o.s[4] = f2b(bb.x); o.s[5] = f2b(bb.y); o.s[6] = f2b(bb.z); o.s[7] = f2b(bb.w);
    } else {
        const int p = pool[(size_t)b * Nf + n];
        o.u = *(const uint4*)(X + ((size_t)b * Nc + p) * Cc + (c8 - Cc));
    }
    *(uint4*)(out + (size_t)row * 2 * Cc + c8) = o.u;
}

// ---------------- per-channel BN scale/shift from sums ----------------
__global__ void bn_finalize(const float* __restrict__ sum, const float* __restrict__ sumsq,
                            const float* __restrict__ g, const float* __restrict__ be,
                            float* __restrict__ scale, float* __restrict__ shift,
                            int Cc, float invM) {
    const int c = blockIdx.x * 256 + threadIdx.x;
    if (c >= Cc) return;
    const float mu = sum[c] * invM;
    const float var = fmaf(sumsq[c], invM, -mu * mu);
    const float sc = g[c] * rsqrtf(var + 1e-5f);
    scale[c] = sc;
    shift[c] = fmaf(-mu, sc, be[c]);
}

extern "C" void kernel_launch(void* const* d_in, const int* in_sizes, int n_in,
                              void* d_out, int out_size, void* d_ws, size_t ws_size,
                              hipStream_t stream) {
    const float* f0     = (const float*)d_in[0];
    const float* f1     = (const float*)d_in[1];
    const float* f2     = (const float*)d_in[2];
    const float* up0_w1 = (const float*)d_in[3];
    const float* up0_g  = (const float*)d_in[5];
    const float* up0_be = (const float*)d_in[6];
    const float* up0_w2 = (const float*)d_in[7];
    const float* up0_b2 = (const float*)d_in[8];
    const float* up1_w1 = (const float*)d_in[9];
    const float* up1_g  = (const float*)d_in[11];
    const float* up1_be = (const float*)d_in[12];
    const float* up1_w2 = (const float*)d_in[13];
    const float* up1_b2 = (const float*)d_in[14];
    const float* sk0_w1 = (const float*)d_in[15];
    const float* sk0_g  = (const float*)d_in[17];
    const float* sk0_be = (const float*)d_in[18];
    const float* sk0_w2 = (const float*)d_in[19];
    const float* sk0_b2 = (const float*)d_in[20];
    const float* sk1_w1 = (const float*)d_in[21];
    const float* sk1_g  = (const float*)d_in[23];
    const float* sk1_be = (const float*)d_in[24];
    const float* sk1_w2 = (const float*)d_in[25];
    const float* sk1_b2 = (const float*)d_in[26];
    const int* pool0    = (const int*)d_in[27];
    const int* pool1    = (const int*)d_in[28];
    float* out = (float*)d_out;

    char* ws = (char*)d_ws;
    size_t off = 0;
    auto alloc = [&](size_t bytes) -> void* {
        void* p = ws + off;
        off += (bytes + 255) & ~(size_t)255;
        return p;
    };
    u16* w_up1_1 = (u16*)alloc((size_t)1024 * 1024 * 2);
    u16* w_up1_2 = (u16*)alloc((size_t)512 * 1024 * 2);
    u16* w_sk1_1 = (u16*)alloc((size_t)1024 * 1024 * 2);
    u16* w_sk1_2 = (u16*)alloc((size_t)512 * 1024 * 2);
    u16* w_up0_1 = (u16*)alloc((size_t)512 * 512 * 2);
    u16* w_up0_2 = (u16*)alloc((size_t)256 * 512 * 2);
    u16* w_sk0_1 = (u16*)alloc((size_t)512 * 512 * 2);
    u16* w_sk0_2 = (u16*)alloc((size_t)256 * 512 * 2);
    float* stats = (float*)alloc((size_t)4 * 4096 * 4);   // per MLP: sum|sumsq|scale|shift x1024
    u16* Hbuf    = (u16*)alloc((size_t)131072 * 512 * 2); // 128 MiB
    u16* Xbuf    = (u16*)alloc((size_t)32768 * 512 * 2);  // 32 MiB
    u16* Catbuf  = (u16*)alloc((size_t)131072 * 512 * 2); // 128 MiB (also holds f2-bf16)

    const dim3 tb(32, 8);
    cvt_transpose_w<<<dim3(32, 32), tb, 0, stream>>>(up1_w1, w_up1_1, 1024, 1024);
    cvt_transpose_w<<<dim3(16, 32), tb, 0, stream>>>(up1_w2, w_up1_2, 1024, 512);
    cvt_transpose_w<<<dim3(32, 32), tb, 0, stream>>>(sk1_w1, w_sk1_1, 1024, 1024);
    cvt_transpose_w<<<dim3(16, 32), tb, 0, stream>>>(sk1_w2, w_sk1_2, 1024, 512);
    cvt_transpose_w<<<dim3(16, 16), tb, 0, stream>>>(up0_w1, w_up0_1, 512, 512);
    cvt_transpose_w<<<dim3(8, 16),  tb, 0, stream>>>(up0_w2, w_up0_2, 512, 256);
    cvt_transpose_w<<<dim3(16, 16), tb, 0, stream>>>(sk0_w1, w_sk0_1, 512, 512);
    cvt_transpose_w<<<dim3(8, 16),  tb, 0, stream>>>(sk0_w2, w_sk0_2, 512, 256);

    hipMemsetAsync(stats, 0, (size_t)4 * 4096 * sizeof(float), stream);
    cvt_f32_bf16<<<(8388608 / 8) / 256, 256, 0, stream>>>(f2, Catbuf, 8388608 / 8);

    float* st0 = stats;
    float* st1 = stats + 4096;
    float* st2 = stats + 8192;
    float* st3 = stats + 12288;

    // ---- up1: (8192x1024)@(1024x1024) -> BN -> ReLU -> @(1024x512) ----
    gemm_bn<false, true, false><<<dim3(8, 64), 256, 0, stream>>>(
        Catbuf, w_up1_1, Hbuf, nullptr, nullptr, nullptr, st0, st0 + 1024, 8192, 1024, 1024);
    bn_finalize<<<4, 256, 0, stream>>>(st0, st0 + 1024, up1_g, up1_be, st0 + 2048, st0 + 3072, 1024, 1.f / 8192.f);
    gemm_bn<true, false, false><<<dim3(4, 64), 256, 0, stream>>>(
        Hbuf, w_up1_2, Xbuf, st0 + 2048, st0 + 3072, up1_b2, nullptr, nullptr, 8192, 512, 1024);

    // ---- gather pool1 + concat f1 -> (32768 x 1024) ----
    gather_concat<<<(4 * 8192 * 128) / 256, 256, 0, stream>>>(f1, Xbuf, pool1, Catbuf, 8192, 2048, 512, 4);

    // ---- skip1: (32768x1024)@(1024x1024) -> BN -> ReLU -> @(1024x512) ----
    gemm_bn<false, true, false><<<dim3(8, 256), 256, 0, stream>>>(
        Catbuf, w_sk1_1, Hbuf, nullptr, nullptr, nullptr, st1, st1 + 1024, 32768, 1024, 1024);
    bn_finalize<<<4, 256, 0, stream>>>(st1, st1 + 1024, sk1_g, sk1_be, st1 + 2048, st1 + 3072, 1024, 1.f / 32768.f);
    gemm_bn<true, false, false><<<dim3(4, 256), 256, 0, stream>>>(
        Hbuf, w_sk1_2, Xbuf, st1 + 2048, st1 + 3072, sk1_b2, nullptr, nullptr, 32768, 512, 1024);

    // ---- up0: (32768x512)@(512x512) -> BN -> ReLU -> @(512x256) ----
    gemm_bn<false, true, false><<<dim3(4, 256), 256, 0, stream>>>(
        Xbuf, w_up0_1, Hbuf, nullptr, nullptr, nullptr, st2, st2 + 1024, 32768, 512, 512);
    bn_finalize<<<2, 256, 0, stream>>>(st2, st2 + 1024, up0_g, up0_be, st2 + 2048, st2 + 3072, 512, 1.f / 32768.f);
    gemm_bn<true, false, false><<<dim3(2, 256), 256, 0, stream>>>(
        Hbuf, w_up0_2, Xbuf, st2 + 2048, st2 + 3072, up0_b2, nullptr, nullptr, 32768, 256, 512);

    // ---- gather pool0 + concat f0 -> (131072 x 512) ----
    gather_concat<<<(4 * 32768 * 64) / 256, 256, 0, stream>>>(f0, Xbuf, pool0, Catbuf, 32768, 8192, 256, 4);

    // ---- skip0: (131072x512)@(512x512) -> BN -> ReLU -> @(512x256) -> fp32 out ----
    gemm_bn<false, true, false><<<dim3(4, 1024), 256, 0, stream>>>(
        Catbuf, w_sk0_1, Hbuf, nullptr, nullptr, nullptr, st3, st3 + 1024, 131072, 512, 512);
    bn_finalize<<<2, 256, 0, stream>>>(st3, st3 + 1024, sk0_g, sk0_be, st3 + 2048, st3 + 3072, 512, 1.f / 131072.f);
    gemm_bn<true, false, true><<<dim3(2, 1024), 256, 0, stream>>>(
        Hbuf, w_sk0_2, out, st3 + 2048, st3 + 3072, sk0_b2, nullptr, nullptr, 131072, 256, 512);
}

// Round 2
// 885.938 us; speedup vs baseline: 1.0435x; 1.0435x over previous
//
#include <hip/hip_runtime.h>

// FeatureDecoder: 4x (Linear -> BN(batch stats) -> ReLU -> Linear) with gathers.
// R2: XCD-aware block swizzle (A-tile L2 reuse across bn), gather+concat fused
// into GEMM1 A-staging (per-lane global_load_lds addresses), vectorized bf16
// epilogue via LDS round-trip. BN split: GEMM1(+stats atomics)/finalize/
// GEMM2(affine+relu fused in A-staging). GEMM1 bias dropped (BN shift-invariant).

typedef unsigned short u16;
typedef __attribute__((ext_vector_type(8))) short bf16x8;
typedef __attribute__((ext_vector_type(4))) float f32x4;

#define EPW 136  // epilogue LDS row stride (u16): 128+8 keeps 16B row alignment,
                 // quad rows shift 16 banks -> <=4-way write aliasing, reads BW-bound

__device__ __forceinline__ float b2f(u16 u) {
    union { unsigned int i; float f; } v; v.i = ((unsigned int)u) << 16; return v.f;
}
__device__ __forceinline__ u16 f2b(float f) {
    union { float f; unsigned int i; } v; v.f = f;
    unsigned int r = v.i + 0x7FFFu + ((v.i >> 16) & 1u);
    return (u16)(r >> 16);
}

__device__ __forceinline__ void gld_lds16(const u16* g, u16* l) {
    __builtin_amdgcn_global_load_lds(
        (const __attribute__((address_space(1))) unsigned int*)g,
        (__attribute__((address_space(3))) unsigned int*)l,
        16, 0, 0);
}

union SMem {
    struct { u16 a[128 * 64]; u16 b[128 * 64]; } st;  // staging (32 KB)
    u16 ep[128 * EPW];                                 // epilogue (34 KB)
};

// ---------------- GEMM: C(MxN) = A(MxK bf16) @ BT(NxK bf16)^T ----------------
// AFFINE_A: A is H; apply relu(H*scale+shift) per K-channel during staging.
// STATS: per-column sum/sumsq of the fp32 accumulator via atomics.
// OUT_F32: write fp32 (scalar), else bf16 via LDS-vectorized stores.
// GATHER: A row r = [F[r, 0:Chalf] | Xg[(r>>nfShift)*Nc + pool[r], 0:Chalf]]
template <bool AFFINE_A, bool STATS, bool OUT_F32, bool GATHER>
__global__ __launch_bounds__(256) void gemm_bn(
    const u16* __restrict__ A, const u16* __restrict__ BT, void* __restrict__ Cout,
    const float* __restrict__ scale, const float* __restrict__ shift,
    const float* __restrict__ bias,
    float* __restrict__ psum, float* __restrict__ psumsq,
    const u16* __restrict__ Xg, const int* __restrict__ pool,
    int nfShift, int Nc, int Chalf,
    int N, int K)
{
    __shared__ __align__(16) SMem sm;

    const int tid  = threadIdx.x;
    const int w    = tid >> 6;
    const int lane = tid & 63;
    const int wm   = w & 1, wn = w >> 1;

    // XCD-aware swizzle: consecutive flat ids round-robin XCDs, so give each
    // XCD (flat&7) a contiguous M-slice with bn varying fastest -> the 128-row
    // A-tile is re-read from the SAME XCD's L2 across all bn column blocks.
    int bm, bn;
    {
        const int flat = (int)(blockIdx.y * gridDim.x + blockIdx.x);
        const int xcd  = flat & 7;
        const int s    = flat >> 3;
        const int nbn  = (int)gridDim.x;               // 2/4/8 (power of two)
        const int lb   = 31 - __builtin_clz(nbn);
        bn = s & (nbn - 1);
        bm = xcd * ((int)gridDim.y >> 3) + (s >> lb);
    }

    const int scol = (lane & 7) * 8;
    const u16* Bg = BT + (size_t)(bn * 128 + w * 32 + (lane >> 3)) * K + scol;

    const u16* agA[4];
    const u16* agX[4];
    if constexpr (GATHER) {
#pragma unroll
        for (int q = 0; q < 4; q++) {
            const int row = bm * 128 + w * 32 + q * 8 + (lane >> 3);
            const int b   = row >> nfShift;
            const int p   = pool[row];                 // pool is [B,Nf] flat = row
            agA[q] = A  + (size_t)row * Chalf + scol;
            agX[q] = Xg + ((size_t)b * Nc + p) * Chalf + scol;
        }
    } else {
#pragma unroll
        for (int q = 0; q < 4; q++)
            agA[q] = A + (size_t)(bm * 128 + w * 32 + q * 8 + (lane >> 3)) * K + scol;
    }

    f32x4 acc[4][4];
    const f32x4 zero = {0.f, 0.f, 0.f, 0.f};
#pragma unroll
    for (int i = 0; i < 4; i++)
#pragma unroll
        for (int j = 0; j < 4; j++) acc[i][j] = zero;

    const int nkt = K >> 6;
    for (int kt = 0; kt < nkt; kt++) {
        const int kof = kt * 64;
        // ---- stage B (async global->LDS, 16B/lane) ----
#pragma unroll
        for (int q = 0; q < 4; q++)
            gld_lds16(Bg + (size_t)(q * 8) * K + kof, &sm.st.b[(w * 32 + q * 8) * 64]);
        // ---- stage A ----
        if constexpr (GATHER) {
            if (kof < Chalf) {
#pragma unroll
                for (int q = 0; q < 4; q++)
                    gld_lds16(agA[q] + kof, &sm.st.a[(w * 32 + q * 8) * 64]);
            } else {
#pragma unroll
                for (int q = 0; q < 4; q++)
                    gld_lds16(agX[q] + (kof - Chalf), &sm.st.a[(w * 32 + q * 8) * 64]);
            }
        } else if constexpr (!AFFINE_A) {
#pragma unroll
            for (int q = 0; q < 4; q++)
                gld_lds16(agA[q] + kof, &sm.st.a[(w * 32 + q * 8) * 64]);
        } else {
            const float4 sc0 = *(const float4*)(scale + kof + scol);
            const float4 sc1 = *(const float4*)(scale + kof + scol + 4);
            const float4 sh0 = *(const float4*)(shift + kof + scol);
            const float4 sh1 = *(const float4*)(shift + kof + scol + 4);
#pragma unroll
            for (int q = 0; q < 4; q++) {
                union { uint4 u; u16 s[8]; } r, o;
                r.u = *(const uint4*)(agA[q] + kof);
                o.s[0] = f2b(fmaxf(b2f(r.s[0]) * sc0.x + sh0.x, 0.f));
                o.s[1] = f2b(fmaxf(b2f(r.s[1]) * sc0.y + sh0.y, 0.f));
                o.s[2] = f2b(fmaxf(b2f(r.s[2]) * sc0.z + sh0.z, 0.f));
                o.s[3] = f2b(fmaxf(b2f(r.s[3]) * sc0.w + sh0.w, 0.f));
                o.s[4] = f2b(fmaxf(b2f(r.s[4]) * sc1.x + sh1.x, 0.f));
                o.s[5] = f2b(fmaxf(b2f(r.s[5]) * sc1.y + sh1.y, 0.f));
                o.s[6] = f2b(fmaxf(b2f(r.s[6]) * sc1.z + sh1.z, 0.f));
                o.s[7] = f2b(fmaxf(b2f(r.s[7]) * sc1.w + sh1.w, 0.f));
                *(uint4*)&sm.st.a[(w * 32 + q * 8 + (lane >> 3)) * 64 + scol] = o.u;
            }
        }
        __syncthreads();
        // ---- compute: 2 k-steps of 32, 16 MFMA each ----
#pragma unroll
        for (int ks = 0; ks < 2; ks++) {
            const int kk = ks * 32 + (lane >> 4) * 8;
            bf16x8 af[4], bfr[4];
#pragma unroll
            for (int i = 0; i < 4; i++)
                af[i] = *(const bf16x8*)&sm.st.a[(wm * 64 + i * 16 + (lane & 15)) * 64 + kk];
#pragma unroll
            for (int j = 0; j < 4; j++)
                bfr[j] = *(const bf16x8*)&sm.st.b[(wn * 64 + j * 16 + (lane & 15)) * 64 + kk];
#pragma unroll
            for (int i = 0; i < 4; i++)
#pragma unroll
                for (int j = 0; j < 4; j++)
                    acc[i][j] = __builtin_amdgcn_mfma_f32_16x16x32_bf16(af[i], bfr[j], acc[i][j], 0, 0, 0);
        }
        __syncthreads();
    }

    // ---- epilogue: C/D layout col=lane&15, row=(lane>>4)*4+reg ----
    const int cl = lane & 15, quad = lane >> 4;
#pragma unroll
    for (int j = 0; j < 4; j++) {
        const int colLocal = wn * 64 + j * 16 + cl;
        const int col = bn * 128 + colLocal;
        float bcol = 0.f;
        if constexpr (!STATS) bcol = bias[col];
        float s = 0.f, ss = 0.f;
#pragma unroll
        for (int i = 0; i < 4; i++) {
            const int rowLocal0 = wm * 64 + i * 16 + quad * 4;
#pragma unroll
            for (int r = 0; r < 4; r++) {
                const float v = acc[i][j][r];
                if constexpr (STATS) { s += v; ss += v * v; }
                const float o = v + bcol;
                if constexpr (OUT_F32)
                    ((float*)Cout)[(size_t)(bm * 128 + rowLocal0 + r) * N + col] = o;
                else
                    sm.ep[(rowLocal0 + r) * EPW + colLocal] = f2b(o);
            }
        }
        if constexpr (STATS) {
            s  += __shfl_xor(s, 16);  s  += __shfl_xor(s, 32);
            ss += __shfl_xor(ss, 16); ss += __shfl_xor(ss, 32);
            if (quad == 0) { atomicAdd(&psum[col], s); atomicAdd(&psumsq[col], ss); }
        }
    }
    if constexpr (!OUT_F32) {
        __syncthreads();
        u16* Cb = (u16*)Cout;
#pragma unroll
        for (int it = 0; it < 8; it++) {
            const int row = it * 16 + (tid >> 4);
            const int c8  = (tid & 15) * 8;
            const uint4 v = *(const uint4*)&sm.ep[row * EPW + c8];
            *(uint4*)(Cb + (size_t)(bm * 128 + row) * N + bn * 128 + c8) = v;
        }
    }
}

// ---------------- W (KxN fp32) -> WT (NxK bf16), tiled transpose ----------------
__global__ void cvt_transpose_w(const float* __restrict__ W, u16* __restrict__ WT, int K, int N) {
    __shared__ float t[32][33];
    const int tx = threadIdx.x, ty = threadIdx.y;
    const int n0 = blockIdx.x * 32, k0 = blockIdx.y * 32;
#pragma unroll
    for (int r = 0; r < 4; r++)
        t[ty + r * 8][tx] = W[(size_t)(k0 + ty + r * 8) * N + n0 + tx];
    __syncthreads();
#pragma unroll
    for (int r = 0; r < 4; r++)
        WT[(size_t)(n0 + ty + r * 8) * K + k0 + tx] = f2b(t[tx][ty + r * 8]);
}

// ---------------- fp32 -> bf16 elementwise (8 elems/thread) ----------------
__global__ void cvt_f32_bf16(const float* __restrict__ x, u16* __restrict__ y, long n8) {
    const long t = (long)blockIdx.x * 256 + threadIdx.x;
    if (t >= n8) return;
    const float4 a = ((const float4*)x)[t * 2];
    const float4 b = ((const float4*)x)[t * 2 + 1];
    union { uint4 u; u16 s[8]; } o;
    o.s[0] = f2b(a.x); o.s[1] = f2b(a.y); o.s[2] = f2b(a.z); o.s[3] = f2b(a.w);
    o.s[4] = f2b(b.x); o.s[5] = f2b(b.y); o.s[6] = f2b(b.z); o.s[7] = f2b(b.w);
    ((uint4*)y)[t] = o.u;
}

// ---------------- per-channel BN scale/shift from sums ----------------
__global__ void bn_finalize(const float* __restrict__ sum, const float* __restrict__ sumsq,
                            const float* __restrict__ g, const float* __restrict__ be,
                            float* __restrict__ scale, float* __restrict__ shift,
                            int Cc, float invM) {
    const int c = blockIdx.x * 256 + threadIdx.x;
    if (c >= Cc) return;
    const float mu = sum[c] * invM;
    const float var = fmaf(sumsq[c], invM, -mu * mu);
    const float sc = g[c] * rsqrtf(var + 1e-5f);
    scale[c] = sc;
    shift[c] = fmaf(-mu, sc, be[c]);
}

extern "C" void kernel_launch(void* const* d_in, const int* in_sizes, int n_in,
                              void* d_out, int out_size, void* d_ws, size_t ws_size,
                              hipStream_t stream) {
    const float* f0     = (const float*)d_in[0];
    const float* f1     = (const float*)d_in[1];
    const float* f2     = (const float*)d_in[2];
    const float* up0_w1 = (const float*)d_in[3];
    const float* up0_g  = (const float*)d_in[5];
    const float* up0_be = (const float*)d_in[6];
    const float* up0_w2 = (const float*)d_in[7];
    const float* up0_b2 = (const float*)d_in[8];
    const float* up1_w1 = (const float*)d_in[9];
    const float* up1_g  = (const float*)d_in[11];
    const float* up1_be = (const float*)d_in[12];
    const float* up1_w2 = (const float*)d_in[13];
    const float* up1_b2 = (const float*)d_in[14];
    const float* sk0_w1 = (const float*)d_in[15];
    const float* sk0_g  = (const float*)d_in[17];
    const float* sk0_be = (const float*)d_in[18];
    const float* sk0_w2 = (const float*)d_in[19];
    const float* sk0_b2 = (const float*)d_in[20];
    const float* sk1_w1 = (const float*)d_in[21];
    const float* sk1_g  = (const float*)d_in[23];
    const float* sk1_be = (const float*)d_in[24];
    const float* sk1_w2 = (const float*)d_in[25];
    const float* sk1_b2 = (const float*)d_in[26];
    const int* pool0    = (const int*)d_in[27];
    const int* pool1    = (const int*)d_in[28];
    float* out = (float*)d_out;

    char* ws = (char*)d_ws;
    size_t off = 0;
    auto alloc = [&](size_t bytes) -> void* {
        void* p = ws + off;
        off += (bytes + 255) & ~(size_t)255;
        return p;
    };
    u16* w_up1_1 = (u16*)alloc((size_t)1024 * 1024 * 2);
    u16* w_up1_2 = (u16*)alloc((size_t)512 * 1024 * 2);
    u16* w_sk1_1 = (u16*)alloc((size_t)1024 * 1024 * 2);
    u16* w_sk1_2 = (u16*)alloc((size_t)512 * 1024 * 2);
    u16* w_up0_1 = (u16*)alloc((size_t)512 * 512 * 2);
    u16* w_up0_2 = (u16*)alloc((size_t)256 * 512 * 2);
    u16* w_sk0_1 = (u16*)alloc((size_t)512 * 512 * 2);
    u16* w_sk0_2 = (u16*)alloc((size_t)256 * 512 * 2);
    float* stats = (float*)alloc((size_t)4 * 4096 * 4);    // per MLP: sum|sumsq|scale|shift
    u16* Hbuf    = (u16*)alloc((size_t)131072 * 512 * 2);  // 134 MB
    u16* Xbuf    = (u16*)alloc((size_t)32768 * 512 * 2);   // 33 MB
    u16* f0b     = (u16*)alloc((size_t)4 * 32768 * 256 * 2); // 67 MB
    u16* f1b     = (u16*)alloc((size_t)4 * 8192 * 512 * 2);  // 33 MB
    u16* f2b_    = (u16*)alloc((size_t)4 * 2048 * 1024 * 2); // 17 MB

    const dim3 tb(32, 8);
    cvt_transpose_w<<<dim3(32, 32), tb, 0, stream>>>(up1_w1, w_up1_1, 1024, 1024);
    cvt_transpose_w<<<dim3(16, 32), tb, 0, stream>>>(up1_w2, w_up1_2, 1024, 512);
    cvt_transpose_w<<<dim3(32, 32), tb, 0, stream>>>(sk1_w1, w_sk1_1, 1024, 1024);
    cvt_transpose_w<<<dim3(16, 32), tb, 0, stream>>>(sk1_w2, w_sk1_2, 1024, 512);
    cvt_transpose_w<<<dim3(16, 16), tb, 0, stream>>>(up0_w1, w_up0_1, 512, 512);
    cvt_transpose_w<<<dim3(8, 16),  tb, 0, stream>>>(up0_w2, w_up0_2, 512, 256);
    cvt_transpose_w<<<dim3(16, 16), tb, 0, stream>>>(sk0_w1, w_sk0_1, 512, 512);
    cvt_transpose_w<<<dim3(8, 16),  tb, 0, stream>>>(sk0_w2, w_sk0_2, 512, 256);

    hipMemsetAsync(stats, 0, (size_t)4 * 4096 * sizeof(float), stream);
    cvt_f32_bf16<<<4096,  256, 0, stream>>>(f2, f2b_, 8388608L / 8);
    cvt_f32_bf16<<<8192,  256, 0, stream>>>(f1, f1b, 16777216L / 8);
    cvt_f32_bf16<<<16384, 256, 0, stream>>>(f0, f0b, 33554432L / 8);

    float* st0 = stats;
    float* st1 = stats + 4096;
    float* st2 = stats + 8192;
    float* st3 = stats + 12288;

    // ---- up1: (8192x1024)@(1024x1024) -> BN -> ReLU -> @(1024x512) ----
    gemm_bn<false, true, false, false><<<dim3(8, 64), 256, 0, stream>>>(
        f2b_, w_up1_1, Hbuf, nullptr, nullptr, nullptr, st0, st0 + 1024,
        nullptr, nullptr, 0, 0, 0, 1024, 1024);
    bn_finalize<<<4, 256, 0, stream>>>(st0, st0 + 1024, up1_g, up1_be, st0 + 2048, st0 + 3072, 1024, 1.f / 8192.f);
    gemm_bn<true, false, false, false><<<dim3(4, 64), 256, 0, stream>>>(
        Hbuf, w_up1_2, Xbuf, st0 + 2048, st0 + 3072, up1_b2, nullptr, nullptr,
        nullptr, nullptr, 0, 0, 0, 512, 1024);

    // ---- skip1: concat[f1|gather(X,pool1)] (32768x1024) @ w -> BN -> ReLU -> @ w2 ----
    gemm_bn<false, true, false, true><<<dim3(8, 256), 256, 0, stream>>>(
        f1b, w_sk1_1, Hbuf, nullptr, nullptr, nullptr, st1, st1 + 1024,
        Xbuf, pool1, 13, 2048, 512, 1024, 1024);
    bn_finalize<<<4, 256, 0, stream>>>(st1, st1 + 1024, sk1_g, sk1_be, st1 + 2048, st1 + 3072, 1024, 1.f / 32768.f);
    gemm_bn<true, false, false, false><<<dim3(4, 256), 256, 0, stream>>>(
        Hbuf, w_sk1_2, Xbuf, st1 + 2048, st1 + 3072, sk1_b2, nullptr, nullptr,
        nullptr, nullptr, 0, 0, 0, 512, 1024);

    // ---- up0: (32768x512)@(512x512) -> BN -> ReLU -> @(512x256) ----
    gemm_bn<false, true, false, false><<<dim3(4, 256), 256, 0, stream>>>(
        Xbuf, w_up0_1, Hbuf, nullptr, nullptr, nullptr, st2, st2 + 1024,
        nullptr, nullptr, 0, 0, 0, 512, 512);
    bn_finalize<<<2, 256, 0, stream>>>(st2, st2 + 1024, up0_g, up0_be, st2 + 2048, st2 + 3072, 512, 1.f / 32768.f);
    gemm_bn<true, false, false, false><<<dim3(2, 256), 256, 0, stream>>>(
        Hbuf, w_up0_2, Xbuf, st2 + 2048, st2 + 3072, up0_b2, nullptr, nullptr,
        nullptr, nullptr, 0, 0, 0, 256, 512);

    // ---- skip0: concat[f0|gather(X,pool0)] (131072x512) @ w -> BN -> ReLU -> @ w2 -> fp32 ----
    gemm_bn<false, true, false, true><<<dim3(4, 1024), 256, 0, stream>>>(
        f0b, w_sk0_1, Hbuf, nullptr, nullptr, nullptr, st3, st3 + 1024,
        Xbuf, pool0, 15, 8192, 256, 512, 512);
    bn_finalize<<<2, 256, 0, stream>>>(st3, st3 + 1024, sk0_g, sk0_be, st3 + 2048, st3 + 3072, 512, 1.f / 131072.f);
    gemm_bn<true, false, true, false><<<dim3(2, 1024), 256, 0, stream>>>(
        Hbuf, w_sk0_2, out, st3 + 2048, st3 + 3072, sk0_b2, nullptr, nullptr,
        nullptr, nullptr, 0, 0, 0, 256, 512);
}